// Round 1
// baseline (166.492 us; speedup 1.0000x reference)
//
#include <hip/hip_runtime.h>

// MergeLayer: out = sigmoid(relu([z[e0]; z[e1]] @ W1 + b1) @ W2 + b2)
// Factored: gi = z@W1_top + b1, gj = z@W1_bot  (node GEMM, 3.28 GF)
//           out[k] = sigmoid(dot(relu(gi[e0k]+gj[e1k]), W2) + b2)  (edge gather)
// gi/gj stored bf16 in workspace (25.6 MB) to halve gather bandwidth.

#define DD 128   // feature dim
#define NC 256   // concat cols (2*HIDDEN halves -> gi | gj)
#define NT 16    // nodes per block in node GEMM
#define KT 16    // k-tile staged in LDS

static __device__ __forceinline__ unsigned short f2bf(float f) {
  unsigned int u = __builtin_bit_cast(unsigned int, f);
  u += 0x7fffu + ((u >> 16) & 1u);   // round-to-nearest-even
  return (unsigned short)(u >> 16);
}
static __device__ __forceinline__ float bflo(unsigned int u) {
  return __builtin_bit_cast(float, u << 16);
}
static __device__ __forceinline__ float bfhi(unsigned int u) {
  return __builtin_bit_cast(float, u & 0xffff0000u);
}

// ---------------- node GEMM: g[n][c] = z[n][:] @ Wcat[:][c] (+b1 for c<128) ---
// Wcat[k][c] = (c<128) ? W1[k][c] : W1[128+k][c-128]   (W1 is [256][128] row-major)
__global__ __launch_bounds__(256) void node_gemm(
    const float* __restrict__ z, const float* __restrict__ W1,
    const float* __restrict__ b1, unsigned short* __restrict__ gi,
    unsigned short* __restrict__ gj, int n_nodes) {
  __shared__ float zs[NT][DD];    // 8 KB
  __shared__ float wsm[KT][NC];   // 16 KB
  const int tid = threadIdx.x;
  const int cx = tid & 63;        // col group: cols 4cx..4cx+3
  const int ny = tid >> 6;        // node group: nodes 4ny..4ny+3
  const int nb = blockIdx.x * NT;

  {  // stage z tile (16 nodes x 128 k), coalesced float4
    const float4* zg = (const float4*)z;
    float4* zl = (float4*)&zs[0][0];
#pragma unroll
    for (int r = 0; r < 2; ++r) {
      int q = tid + r * 256;                 // 512 float4 total
      int node = nb + (q >> 5);              // 32 float4 per node row
      if (node >= n_nodes) node = n_nodes - 1;
      zl[q] = zg[(size_t)node * 32 + (q & 31)];
    }
  }

  float4 acc[4];
  {
    float4 bias = make_float4(0.f, 0.f, 0.f, 0.f);
    if (cx < 32) bias = ((const float4*)b1)[cx];  // b1 folded into gi half
    acc[0] = bias; acc[1] = bias; acc[2] = bias; acc[3] = bias;
  }

  for (int kt = 0; kt < DD; kt += KT) {
    __syncthreads();
    {  // stage Wcat[kt..kt+16) x [0..256): two contiguous W1 slabs
      const float4* wg = (const float4*)W1;
#pragma unroll
      for (int r = 0; r < 2; ++r) {
        int qq = tid + r * 256;          // 512 float4 per slab
        int k  = qq >> 5;
        int c4 = qq & 31;
        ((float4*)&wsm[k][0])[c4]   = wg[kt * 32 + qq];           // top half
        ((float4*)&wsm[k][128])[c4] = wg[(128 + kt) * 32 + qq];   // bottom half
      }
    }
    __syncthreads();
#pragma unroll
    for (int k4 = 0; k4 < KT; k4 += 4) {
      float4 zr[4];
#pragma unroll
      for (int n = 0; n < 4; ++n)
        zr[n] = *(const float4*)&zs[ny * 4 + n][kt + k4];  // wave-uniform -> LDS broadcast
#pragma unroll
      for (int kk = 0; kk < 4; ++kk) {
        float4 w = ((const float4*)&wsm[k4 + kk][0])[cx];  // stride-16B dense, no conflicts
#pragma unroll
        for (int n = 0; n < 4; ++n) {
          float zv = kk == 0 ? zr[n].x : kk == 1 ? zr[n].y : kk == 2 ? zr[n].z : zr[n].w;
          acc[n].x = fmaf(zv, w.x, acc[n].x);
          acc[n].y = fmaf(zv, w.y, acc[n].y);
          acc[n].z = fmaf(zv, w.z, acc[n].z);
          acc[n].w = fmaf(zv, w.w, acc[n].w);
        }
      }
    }
  }

  const int c = cx * 4;
#pragma unroll
  for (int n = 0; n < 4; ++n) {
    int node = nb + ny * 4 + n;
    if (node < n_nodes) {
      ushort4 o;
      o.x = f2bf(acc[n].x); o.y = f2bf(acc[n].y);
      o.z = f2bf(acc[n].z); o.w = f2bf(acc[n].w);
      if (c < 128)
        *(ushort4*)&gi[(size_t)node * 128 + c] = o;
      else
        *(ushort4*)&gj[(size_t)node * 128 + (c - 128)] = o;
    }
  }
}

// ---------------- edge phase: 8 lanes per edge, each lane covers 16 channels --
static __device__ __forceinline__ float dot8(uint4 a, uint4 b, float4 w0, float4 w1) {
  float s;
  s = fmaxf(bflo(a.x) + bflo(b.x), 0.f) * w0.x;
  s = fmaf(fmaxf(bfhi(a.x) + bfhi(b.x), 0.f), w0.y, s);
  s = fmaf(fmaxf(bflo(a.y) + bflo(b.y), 0.f), w0.z, s);
  s = fmaf(fmaxf(bfhi(a.y) + bfhi(b.y), 0.f), w0.w, s);
  s = fmaf(fmaxf(bflo(a.z) + bflo(b.z), 0.f), w1.x, s);
  s = fmaf(fmaxf(bfhi(a.z) + bfhi(b.z), 0.f), w1.y, s);
  s = fmaf(fmaxf(bflo(a.w) + bflo(b.w), 0.f), w1.z, s);
  s = fmaf(fmaxf(bfhi(a.w) + bfhi(b.w), 0.f), w1.w, s);
  return s;
}

__global__ __launch_bounds__(256) void edge_mlp(
    const int* __restrict__ e, const unsigned short* __restrict__ gi,
    const unsigned short* __restrict__ gj, const float* __restrict__ W2,
    const float* __restrict__ b2, float* __restrict__ out, int E) {
  __shared__ float w2s[128];
  if (threadIdx.x < 128) w2s[threadIdx.x] = W2[threadIdx.x];
  __syncthreads();
  const int lane = threadIdx.x & 63;
  const int gw   = (int)((blockIdx.x * 256u + threadIdx.x) >> 6);
  const int edge = gw * 8 + (lane >> 3);
  const int part = lane & 7;
  float acc = 0.f;
  if (edge < E) {
    const int i = e[edge];
    const int j = e[E + edge];
    // 8 lanes of a wave cover one 256B row: each 16B lane-load is part of a
    // fully-consumed 128B cache line within the same instruction.
    const uint4* pi = (const uint4*)(gi + (size_t)i * 128);
    const uint4* pj = (const uint4*)(gj + (size_t)j * 128);
    uint4 a0 = pi[part * 2 + 0];
    uint4 a1 = pi[part * 2 + 1];
    uint4 c0 = pj[part * 2 + 0];
    uint4 c1 = pj[part * 2 + 1];
    const float4* wv = (const float4*)&w2s[part * 16];
    float4 w0 = wv[0], w1 = wv[1], w2 = wv[2], w3 = wv[3];
    acc = dot8(a0, c0, w0, w1) + dot8(a1, c1, w2, w3);
  }
  acc += __shfl_xor(acc, 1);
  acc += __shfl_xor(acc, 2);
  acc += __shfl_xor(acc, 4);
  if (edge < E && part == 0) {
    float x = acc + b2[0];
    out[edge] = 1.f / (1.f + __expf(-x));
  }
}

// ---------------- fallback (only if workspace is too small): wave per edge ----
__global__ __launch_bounds__(256) void edge_direct(
    const int* __restrict__ e, const float* __restrict__ z,
    const float* __restrict__ W1, const float* __restrict__ b1,
    const float* __restrict__ W2, const float* __restrict__ b2,
    float* __restrict__ out, int E) {
  const int lane = threadIdx.x & 63;
  const int edge = (int)((blockIdx.x * 256u + threadIdx.x) >> 6);
  if (edge >= E) return;  // wave-uniform exit
  const int i = e[edge], j = e[E + edge];
  const float* zi = z + (size_t)i * 128;
  const float* zj = z + (size_t)j * 128;
  const int c0 = lane * 2;
  float h0 = b1[c0], h1 = b1[c0 + 1];
  for (int k = 0; k < 128; ++k) {
    float a = zi[k], b = zj[k];
    float2 wt = *(const float2*)&W1[(size_t)k * 128 + c0];
    float2 wb = *(const float2*)&W1[(size_t)(128 + k) * 128 + c0];
    h0 = fmaf(a, wt.x, h0); h1 = fmaf(a, wt.y, h1);
    h0 = fmaf(b, wb.x, h0); h1 = fmaf(b, wb.y, h1);
  }
  float s = fmaxf(h0, 0.f) * W2[c0] + fmaxf(h1, 0.f) * W2[c0 + 1];
#pragma unroll
  for (int off = 1; off < 64; off <<= 1) s += __shfl_xor(s, off);
  if (lane == 0) out[edge] = 1.f / (1.f + __expf(-(s + b2[0])));
}

extern "C" void kernel_launch(void* const* d_in, const int* in_sizes, int n_in,
                              void* d_out, int out_size, void* d_ws, size_t ws_size,
                              hipStream_t stream) {
  const float* z  = (const float*)d_in[0];
  const int*   e  = (const int*)d_in[1];
  const float* W1 = (const float*)d_in[2];
  const float* b1 = (const float*)d_in[3];
  const float* W2 = (const float*)d_in[4];
  const float* b2 = (const float*)d_in[5];
  float* out = (float*)d_out;
  const int n_nodes = in_sizes[0] / DD;  // 50000
  const int E = in_sizes[1] / 2;         // 600000

  const size_t g_bytes = (size_t)n_nodes * DD * sizeof(unsigned short);
  if (ws_size >= 2 * g_bytes) {
    unsigned short* gi = (unsigned short*)d_ws;
    unsigned short* gj = (unsigned short*)((char*)d_ws + g_bytes);
    node_gemm<<<(n_nodes + NT - 1) / NT, 256, 0, stream>>>(z, W1, b1, gi, gj, n_nodes);
    const int waves = (E + 7) / 8;
    edge_mlp<<<(waves + 3) / 4, 256, 0, stream>>>(e, gi, gj, W2, b2, out, E);
  } else {
    edge_direct<<<(E + 3) / 4, 256, 0, stream>>>(e, z, W1, b1, W2, b2, out, E);
  }
}

// Round 2
// 137.925 us; speedup vs baseline: 1.2071x; 1.2071x over previous
//
#include <hip/hip_runtime.h>

// MergeLayer: out = sigmoid(relu([z[e0]; z[e1]] @ W1 + b1) @ W2 + b2)
// Factored: g = z @ Wcat (+b1 on gi half)  -- node-level GEMM via bf16 MFMA
//           out[k] = sigmoid(dot(relu(gi[e0]+gj[e1]), W2) + b2)  -- edge gather
// ws layout: gi (N*128 bf16) | gj (N*128 bf16) | Wt (256x128 bf16, 64KB)

#define DD 128

typedef __attribute__((ext_vector_type(8))) short short8;
typedef __attribute__((ext_vector_type(4))) float floatx4;

static __device__ __forceinline__ unsigned short f2bf(float f) {
  unsigned int u = __builtin_bit_cast(unsigned int, f);
  u += 0x7fffu + ((u >> 16) & 1u);   // round-to-nearest-even
  return (unsigned short)(u >> 16);
}
static __device__ __forceinline__ float bflo(unsigned int u) {
  return __builtin_bit_cast(float, u << 16);
}
static __device__ __forceinline__ float bfhi(unsigned int u) {
  return __builtin_bit_cast(float, u & 0xffff0000u);
}

// ---------- prelude: Wt[c][k] = Wcat[k][c] as bf16 (B^T for MFMA b-frags) ----
// Wcat[k][c] = (c<128) ? W1[k][c] : W1[128+k][c-128];  W1 is [256][128] fp32.
__global__ __launch_bounds__(256) void wt_build(
    const float* __restrict__ W1, unsigned short* __restrict__ Wt) {
  const int g = blockIdx.x * 256 + threadIdx.x;  // 8192 threads total
  const int c = g >> 5;                          // 0..255
  const int kq = (g & 31) * 4;                   // 0..124
  const float* src = (c < 128) ? (W1 + c) : (W1 + 128 * 128 + (c - 128));
  ushort4 o;
  o.x = f2bf(src[(size_t)(kq + 0) * 128]);
  o.y = f2bf(src[(size_t)(kq + 1) * 128]);
  o.z = f2bf(src[(size_t)(kq + 2) * 128]);
  o.w = f2bf(src[(size_t)(kq + 3) * 128]);
  *(ushort4*)&Wt[c * 128 + kq] = o;
}

// ---------- node GEMM via mfma_f32_16x16x32_bf16 -----------------------------
// Block: 256 threads = 4 waves, 128 nodes. Wave w: nodes [nb+32w, nb+32w+32).
// Per wave: 2 M-subtiles x 16 N-tiles x 4 k-steps = 128 MFMA.
__global__ __launch_bounds__(256) void node_mfma(
    const float* __restrict__ z, const unsigned short* __restrict__ Wt,
    const float* __restrict__ b1, unsigned short* __restrict__ gi,
    unsigned short* __restrict__ gj, int n_nodes) {
  __shared__ unsigned short zb[128 * 136];  // 34.8 KB; row stride 136 (2-way=free)
  const int tid = threadIdx.x;
  const int nb = blockIdx.x * 128;

  // stage z tile -> bf16 LDS (coalesced float4 reads)
#pragma unroll
  for (int i = 0; i < 16; ++i) {
    int q = tid + i * 256;            // 4096 float4 = 128 nodes x 32
    int nl = q >> 5;
    int node = nb + nl; if (node >= n_nodes) node = n_nodes - 1;
    float4 v = ((const float4*)z)[(size_t)node * 32 + (q & 31)];
    ushort4 o;
    o.x = f2bf(v.x); o.y = f2bf(v.y); o.z = f2bf(v.z); o.w = f2bf(v.w);
    *(ushort4*)&zb[nl * 136 + (q & 31) * 4] = o;
  }
  __syncthreads();

  const int w = tid >> 6, lane = tid & 63;
  const int l15 = lane & 15, quad = lane >> 4;

  // A fragments: A[m=lane&15][k=quad*8+j]  (m89/m120-verified layout)
  short8 a[2][4];
#pragma unroll
  for (int u = 0; u < 2; ++u)
#pragma unroll
    for (int s = 0; s < 4; ++s)
      a[u][s] = *(const short8*)&zb[(w * 32 + u * 16 + l15) * 136 + s * 32 + quad * 8];

  floatx4 acc[2][16];
#pragma unroll
  for (int t = 0; t < 16; ++t) {
    float bias = (t < 8) ? b1[t * 16 + l15] : 0.f;  // b1 folded into gi half
    floatx4 b4 = {bias, bias, bias, bias};
    acc[0][t] = b4; acc[1][t] = b4;
  }

  // B fragments straight from global Wt (64KB, L1/L2-hot): b[j]=Wt[n][k]
#pragma unroll
  for (int t = 0; t < 16; ++t) {
    const unsigned short* wrow = Wt + (size_t)(t * 16 + l15) * 128 + quad * 8;
#pragma unroll
    for (int s = 0; s < 4; ++s) {
      short8 b = *(const short8*)(wrow + s * 32);
      acc[0][t] = __builtin_amdgcn_mfma_f32_16x16x32_bf16(a[0][s], b, acc[0][t], 0, 0, 0);
      acc[1][t] = __builtin_amdgcn_mfma_f32_16x16x32_bf16(a[1][s], b, acc[1][t], 0, 0, 0);
    }
  }

  // epilogue: C/D layout col=lane&15, row=quad*4+reg (m89/m91-verified)
#pragma unroll
  for (int u = 0; u < 2; ++u)
#pragma unroll
    for (int t = 0; t < 16; ++t) {
      unsigned short* base = (t < 8) ? gi : gj;
      const int cc = t * 16 + l15 - ((t < 8) ? 0 : 128);
#pragma unroll
      for (int r = 0; r < 4; ++r) {
        int node = nb + w * 32 + u * 16 + quad * 4 + r;
        if (node < n_nodes) base[(size_t)node * 128 + cc] = f2bf(acc[u][t][r]);
      }
    }
}

// ---------- edge phase: 8 lanes per edge, full-cache-line loads ---------------
static __device__ __forceinline__ float dot8(uint4 a, uint4 b, float4 w0, float4 w1) {
  float s;
  s = fmaxf(bflo(a.x) + bflo(b.x), 0.f) * w0.x;
  s = fmaf(fmaxf(bfhi(a.x) + bfhi(b.x), 0.f), w0.y, s);
  s = fmaf(fmaxf(bflo(a.y) + bflo(b.y), 0.f), w0.z, s);
  s = fmaf(fmaxf(bfhi(a.y) + bfhi(b.y), 0.f), w0.w, s);
  s = fmaf(fmaxf(bflo(a.z) + bflo(b.z), 0.f), w1.x, s);
  s = fmaf(fmaxf(bfhi(a.z) + bfhi(b.z), 0.f), w1.y, s);
  s = fmaf(fmaxf(bflo(a.w) + bflo(b.w), 0.f), w1.z, s);
  s = fmaf(fmaxf(bfhi(a.w) + bfhi(b.w), 0.f), w1.w, s);
  return s;
}

__global__ __launch_bounds__(256) void edge_mlp(
    const int* __restrict__ e, const unsigned short* __restrict__ gi,
    const unsigned short* __restrict__ gj, const float* __restrict__ W2,
    const float* __restrict__ b2, float* __restrict__ out, int E) {
  __shared__ float w2s[128];
  if (threadIdx.x < 128) w2s[threadIdx.x] = W2[threadIdx.x];
  __syncthreads();
  const int lane = threadIdx.x & 63;
  const int gw   = (int)((blockIdx.x * 256u + threadIdx.x) >> 6);
  const int edge = gw * 8 + (lane >> 3);
  const int p    = lane & 7;
  float acc = 0.f;
  if (edge < E) {
    const int i = e[edge];
    const int j = e[E + edge];
    // lane p reads bytes [16p,16p+16) then [128+16p,...): each instruction
    // consumes whole 128B lines of the 8 gathered rows.
    const uint4* pi = (const uint4*)(gi + (size_t)i * 128);
    const uint4* pj = (const uint4*)(gj + (size_t)j * 128);
    uint4 a0 = pi[p], a1 = pi[8 + p];
    uint4 c0 = pj[p], c1 = pj[8 + p];
    const float4* wv = (const float4*)w2s;
    acc = dot8(a0, c0, wv[p * 2], wv[p * 2 + 1]) +
          dot8(a1, c1, wv[16 + p * 2], wv[16 + p * 2 + 1]);
  }
  acc += __shfl_xor(acc, 1);
  acc += __shfl_xor(acc, 2);
  acc += __shfl_xor(acc, 4);
  if (edge < E && p == 0) {
    float x = acc + b2[0];
    out[edge] = 1.f / (1.f + __expf(-x));
  }
}

// ---------- fallback (workspace too small): wave per edge ---------------------
__global__ __launch_bounds__(256) void edge_direct(
    const int* __restrict__ e, const float* __restrict__ z,
    const float* __restrict__ W1, const float* __restrict__ b1,
    const float* __restrict__ W2, const float* __restrict__ b2,
    float* __restrict__ out, int E) {
  const int lane = threadIdx.x & 63;
  const int edge = (int)((blockIdx.x * 256u + threadIdx.x) >> 6);
  if (edge >= E) return;
  const int i = e[edge], j = e[E + edge];
  const float* zi = z + (size_t)i * 128;
  const float* zj = z + (size_t)j * 128;
  const int c0 = lane * 2;
  float h0 = b1[c0], h1 = b1[c0 + 1];
  for (int k = 0; k < 128; ++k) {
    float a = zi[k], b = zj[k];
    float2 wt = *(const float2*)&W1[(size_t)k * 128 + c0];
    float2 wb = *(const float2*)&W1[(size_t)(128 + k) * 128 + c0];
    h0 = fmaf(a, wt.x, h0); h1 = fmaf(a, wt.y, h1);
    h0 = fmaf(b, wb.x, h0); h1 = fmaf(b, wb.y, h1);
  }
  float s = fmaxf(h0, 0.f) * W2[c0] + fmaxf(h1, 0.f) * W2[c0 + 1];
#pragma unroll
  for (int off = 1; off < 64; off <<= 1) s += __shfl_xor(s, off);
  if (lane == 0) out[edge] = 1.f / (1.f + __expf(-(s + b2[0])));
}

extern "C" void kernel_launch(void* const* d_in, const int* in_sizes, int n_in,
                              void* d_out, int out_size, void* d_ws, size_t ws_size,
                              hipStream_t stream) {
  const float* z  = (const float*)d_in[0];
  const int*   e  = (const int*)d_in[1];
  const float* W1 = (const float*)d_in[2];
  const float* b1 = (const float*)d_in[3];
  const float* W2 = (const float*)d_in[4];
  const float* b2 = (const float*)d_in[5];
  float* out = (float*)d_out;
  const int n_nodes = in_sizes[0] / DD;  // 50000
  const int E = in_sizes[1] / 2;         // 600000

  const size_t g_bytes = (size_t)n_nodes * DD * sizeof(unsigned short);
  const size_t wt_bytes = 256 * 128 * sizeof(unsigned short);  // 64 KB
  if (ws_size >= 2 * g_bytes + wt_bytes) {
    unsigned short* gi = (unsigned short*)d_ws;
    unsigned short* gj = (unsigned short*)((char*)d_ws + g_bytes);
    unsigned short* Wt = (unsigned short*)((char*)d_ws + 2 * g_bytes);
    wt_build<<<32, 256, 0, stream>>>(W1, Wt);
    node_mfma<<<(n_nodes + 127) / 128, 256, 0, stream>>>(z, Wt, b1, gi, gj, n_nodes);
    const int waves = (E + 7) / 8;
    edge_mlp<<<(waves + 3) / 4, 256, 0, stream>>>(e, gi, gj, W2, b2, out, E);
  } else {
    edge_direct<<<(E + 3) / 4, 256, 0, stream>>>(e, z, W1, b1, W2, b2, out, E);
  }
}